// Round 4
// baseline (104.171 us; speedup 1.0000x reference)
//
#include <hip/hip_runtime.h>

typedef __attribute__((ext_vector_type(8))) short bf16x8;
typedef __attribute__((ext_vector_type(8))) _Float16 f16x8;
typedef __attribute__((ext_vector_type(4))) float f32x4;
typedef __attribute__((ext_vector_type(4))) _Float16 f16x4;
typedef __attribute__((ext_vector_type(2))) _Float16 f16x2;

#define NPTS   40000
#define MOUT   40000
#define EDG    500000
#define FIN    32
#define COUT   64
#define KP     15
#define KFDIM  (KP * FIN)          // 480
#define EXTENT 0.6f

// Block agg tile: 16 segments x 488 f16 (976B rows = 61*16B, conflict-free b128)
#define ASTR 488

#define FEAT_BLKS  (NPTS * FIN / 1024)            // 1250
#define PTS_BLKS   ((NPTS + 255) / 256)           // 157
#define OP_BLKS    ((MOUT + 255) / 256)           // 157
#define ROW_BLKS   ((EDG + 255) / 256)            // 1954
#define WT_BLKS    (KFDIM * COUT / 256)           // 120
#define PRE_BLKS   (FEAT_BLKS + PTS_BLKS + OP_BLKS + ROW_BLKS + WT_BLKS)

__device__ __forceinline__ short f2bf(float x) {
    union { float f; unsigned u; } v; v.f = x;
    unsigned r = (v.u + 0x7fffu + ((v.u >> 16) & 1u)) >> 16;
    return (short)r;
}

// ============================================================================
// Preprocess (ONE launch, branch by block range) — unchanged.
// ============================================================================
__global__ __launch_bounds__(256) void preprocess_all(
    const float* __restrict__ features, _Float16* __restrict__ feat_i,
    const float* __restrict__ pts, float4* __restrict__ p4,
    const float* __restrict__ opts, float4* __restrict__ op4,
    const int* __restrict__ seg_ids, int* __restrict__ row_start,
    const float* __restrict__ k_values, _Float16* __restrict__ w_t)
{
    const int bid = blockIdx.x;
    if (bid < FEAT_BLKS) {
        const int d0 = (bid * 256 + threadIdx.x) * 4;
        #pragma unroll
        for (int u = 0; u < 4; ++u) {
            const int d = d0 + u;
            const int p = d >> 5, q = d & 31;
            const int fp = q >> 1, h = q & 1;
            feat_i[d] = (_Float16)features[p * FIN + fp + 16 * h];
        }
    } else if (bid < FEAT_BLKS + PTS_BLKS) {
        const int i = (bid - FEAT_BLKS) * 256 + threadIdx.x;
        if (i < NPTS) {
            const float* p = pts + 3 * i;
            p4[i] = make_float4(p[0], p[1], p[2], 0.f);
        }
    } else if (bid < FEAT_BLKS + PTS_BLKS + OP_BLKS) {
        const int i = (bid - FEAT_BLKS - PTS_BLKS) * 256 + threadIdx.x;
        if (i < MOUT) {
            const float* p = opts + 3 * i;
            op4[i] = make_float4(p[0], p[1], p[2], 0.f);
        }
    } else if (bid < FEAT_BLKS + PTS_BLKS + OP_BLKS + ROW_BLKS) {
        const int e = (bid - FEAT_BLKS - PTS_BLKS - OP_BLKS) * 256 + threadIdx.x;
        if (e >= EDG) return;
        const int cur  = seg_ids[e];
        const int prev = (e == 0) ? -1 : seg_ids[e - 1];
        for (int m = prev + 1; m <= cur; ++m) row_start[m] = e;
        if (e == EDG - 1)
            for (int m = cur + 1; m <= MOUT; ++m) row_start[m] = EDG;
    } else {
        const int d = (bid - FEAT_BLKS - PTS_BLKS - OP_BLKS - ROW_BLKS) * 256
                      + threadIdx.x;                 // 0 .. 30719
        const int c = d / KFDIM, r = d % KFDIM;
        const int k = r >> 5, q = r & 31;
        const int fp = q >> 1, h = q & 1;
        w_t[d] = (_Float16)k_values[(k * FIN + fp + 16 * h) * COUT + c];
    }
}

// ============================================================================
// Fused kernel: block = 16 segments.
// Phase 1 R17 change: ZERO-LDS phase-1 step. Each lane gathers/computes its
// MFMA fragments DIRECTLY (no staging transpose):
//   A-frag: lane (quad,l16) computes w[kpoint=l16][edge=es+quad*4+j] itself
//           (1 kpoint/lane from l16; 4 point gathers/lane — all 16 lanes of
//           a quad-group load the SAME 4 points -> coalesced broadcast).
//   B-frag: 4 dword gathers feat_i[nb*32 + 2*l16] = (blo,bhi) pairs; within
//           a quad-group the 16 lanes read 64B contiguous -> fully coalesced.
// Removes the LDS write->lgkmcnt->read round-trip (~150-200cy) and both
// fences from the per-step serial chain; consume = VALU(4 sqrt) + 2 MFMA.
// R15 nbr window (shfl) + R16 1-step-ahead prefetch retained. Arithmetic is
// source-identical -> bit-identical output. Stage LDS freed (25.3->15.6KB).
// (256,5) kept from R16 to isolate this structural change.
// Tripwire: >105us or absmax change -> revert to R16.
// ============================================================================
__global__ __launch_bounds__(256, 5) void kpconv_fused2(
    const float4* __restrict__ points4,
    const _Float16* __restrict__ feat_i,
    const float4* __restrict__ op4,
    const int*   __restrict__ nbr_idx,
    const int*   __restrict__ row_start,
    const float* __restrict__ k_points,
    const _Float16* __restrict__ w_t,
    float* __restrict__ out)
{
    __shared__ __align__(16) _Float16 aggT[16 * ASTR];          // 15616 B

    const int tid  = threadIdx.x;
    const int wave = tid >> 6;
    const int lane = tid & 63;
    const int quad = lane >> 4;
    const int l16  = lane & 15;
    const int m0   = blockIdx.x * 16;

    // per-lane kernel point (A-fragment row = l16)
    const int  myk = l16 < KP ? l16 : 0;
    const float kxx = k_points[myk * 3 + 0];
    const float kyy = k_points[myk * 3 + 1];
    const float kzz = k_points[myk * 3 + 2];
    const bool  vk  = (l16 < KP);
    const float inv_ext = 1.f / EXTENT;

    // ---- segment bounds for this wave's 4 segments (contiguous edge range)
    int rs[5];
    #pragma unroll
    for (int i = 0; i < 5; ++i) rs[i] = row_start[m0 + wave * 4 + i];

    // next-nonempty-segment start cascade; sentinel = rs[4] (never consumed)
    int nstart[4];
    nstart[3] = rs[4];
    nstart[2] = (rs[3] < rs[4]) ? rs[3] : rs[4];
    nstart[1] = (rs[2] < rs[3]) ? rs[2] : nstart[2];
    nstart[0] = (rs[1] < rs[2]) ? rs[1] : nstart[1];
    const int fstart = (rs[0] < rs[1]) ? rs[0] : nstart[0];

    // ---- nbr window + prefetch state (named regs, rule-#20 safe) ----
    int wb = -0x40000000;     // forces initial window load
    int nbrreg = 0;
    float4 p0n, p1n, p2n, p3n;
    unsigned f0n = 0, f1n = 0, f2n = 0, f3n = 0;
    p0n = p1n = p2n = p3n = make_float4(0.f, 0.f, 0.f, 0.f);

    // prefetch gathers for step at uniform edge offset `es`
    auto pref = [&](int es) {
        if (es + 15 > wb + 63) {                 // wave-uniform slide
            wb = es;
            const int a = wb + lane;
            nbrreg = nbr_idx[a < EDG ? a : EDG - 1];
        }
        const int base = es - wb + quad * 4;
        const int n0 = __shfl(nbrreg, base + 0);
        const int n1 = __shfl(nbrreg, base + 1);
        const int n2 = __shfl(nbrreg, base + 2);
        const int n3 = __shfl(nbrreg, base + 3);
        p0n = points4[n0];
        p1n = points4[n1];
        p2n = points4[n2];
        p3n = points4[n3];
        f0n = *(const unsigned*)(feat_i + n0 * FIN + 2 * l16);
        f1n = *(const unsigned*)(feat_i + n1 * FIN + 2 * l16);
        f2n = *(const unsigned*)(feat_i + n2 * FIN + 2 * l16);
        f3n = *(const unsigned*)(feat_i + n3 * FIN + 2 * l16);
    };

    pref(fstart);   // first step of first nonempty segment (or dummy)

    // ---- Phase 1: 4 segments, pipelined step stream, no LDS ----
    #pragma unroll
    for (int j = 0; j < 4; ++j) {
        const int e0 = rs[j];
        const int e1 = rs[j + 1];
        const float4 o = op4[m0 + wave * 4 + j];

        f32x4 c_lo = {0.f, 0.f, 0.f, 0.f};
        f32x4 c_hi = {0.f, 0.f, 0.f, 0.f};

        for (int es = e0; es < e1; es += 16) {
            // take current step's prefetched data, then issue next step's
            const float4  P0 = p0n, P1 = p1n, P2 = p2n, P3 = p3n;
            const unsigned F0 = f0n, F1 = f1n, F2 = f2n, F3 = f3n;
            const int nes = (es + 16 < e1) ? es + 16 : nstart[j];
            pref(nes);

            // ---- A-fragment: w[kpoint=l16][edge=es+quad*4+jj] in-lane ----
            f16x4 af;
#define EDGE_W(jj, Pj)                                                        \
            {                                                                 \
                const float rx = Pj.x - o.x, ry = Pj.y - o.y, rz = Pj.z - o.z;\
                const float dx = rx - kxx, dy = ry - kyy, dz = rz - kzz;      \
                float w = 1.f - sqrtf(dx*dx + dy*dy + dz*dz) * inv_ext;       \
                w = w > 0.f ? w : 0.f;                                        \
                if (!vk || (es + quad * 4 + jj) >= e1) w = 0.f;               \
                af[jj] = (_Float16)w;                                         \
            }
            EDGE_W(0, P0)
            EDGE_W(1, P1)
            EDGE_W(2, P2)
            EDGE_W(3, P3)
#undef EDGE_W

            // ---- B-fragment: de-interleave (lo,hi) dword pairs ----
            union { unsigned u; f16x2 h; } U0, U1, U2, U3;
            U0.u = F0; U1.u = F1; U2.u = F2; U3.u = F3;
            const f16x4 blo = {U0.h[0], U1.h[0], U2.h[0], U3.h[0]};
            const f16x4 bhi = {U0.h[1], U1.h[1], U2.h[1], U3.h[1]};

            c_lo = __builtin_amdgcn_mfma_f32_16x16x16f16(af, blo, c_lo, 0, 0, 0);
            c_hi = __builtin_amdgcn_mfma_f32_16x16x16f16(af, bhi, c_hi, 0, 0, 0);
        }

        // D -> agg tile row (interleaved kf order): byte = k*64 + l16*4
        _Float16* dst = aggT + (wave * 4 + j) * ASTR;
        #pragma unroll
        for (int r = 0; r < 4; ++r) {
            const int krow = quad * 4 + r;
            if (krow < KP) {
                f16x2 v = {(_Float16)c_lo[r], (_Float16)c_hi[r]};
                *(f16x2*)(dst + krow * 32 + 2 * l16) = v;
            }
        }
    }

    __syncthreads();

    // ---- Phase 2: C[16 segs x 16 cols] per wave, B in-loop from w_t ----
    const int bcol = wave * 16 + l16;
    const _Float16* wrow = w_t + (size_t)bcol * KFDIM + quad * 8;
    const _Float16* arow = aggT + l16 * ASTR + quad * 8;

    f32x4 c = {0.f, 0.f, 0.f, 0.f};
    #pragma unroll
    for (int s = 0; s < 15; ++s) {
        const f16x8 a = *(const f16x8*)(arow + 32 * s);
        const f16x8 b = *(const f16x8*)(wrow + 32 * s);
        c = __builtin_amdgcn_mfma_f32_16x16x32_f16(a, b, c, 0, 0, 0);
    }

    // C/D: col = lane&15 (-> bcol), row = quad*4 + r (= local segment)
    #pragma unroll
    for (int r = 0; r < 4; ++r)
        out[(m0 + quad * 4 + r) * COUT + bcol] = c[r];
}

// ============================================================================
// Fallback (small ws, needs 38.4 MB): binary-search K=32 agg + plain gemm.
// ============================================================================
__global__ __launch_bounds__(256, 4) void kpconv_agg_fallback(
    const float* __restrict__ points,
    const float* __restrict__ features,
    const float* __restrict__ output_points,
    const int*   __restrict__ nbr_idx,
    const int*   __restrict__ seg_ids,
    const float* __restrict__ k_points,
    _Float16* __restrict__ agg_g)
{
    __shared__ int seg_start[5];

    const int tid = threadIdx.x;
    const int m0  = blockIdx.x * 4;

    if (tid <= 4) {
        const int target = m0 + tid;
        int lo = 0, hi = EDG;
        while (lo < hi) {
            int mid = (lo + hi) >> 1;
            if (seg_ids[mid] < target) lo = mid + 1; else hi = mid;
        }
        seg_start[tid] = lo;
    }
    __syncthreads();

    const int wave = tid >> 6;
    const int lane = tid & 63;
    const int quad = lane >> 4;
    const int l16  = lane & 15;

    const int m = m0 + wave;
    const float ox = output_points[m * 3 + 0];
    const float oy = output_points[m * 3 + 1];
    const float oz = output_points[m * 3 + 2];

    const int myk = l16 < KP ? l16 : 0;
    const float kpx = k_points[myk * 3 + 0];
    const float kpy = k_points[myk * 3 + 1];
    const float kpz = k_points[myk * 3 + 2];
    const float inv_ext = 1.f / EXTENT;

    const int e0 = seg_start[wave], e1 = seg_start[wave + 1];

    f32x4 c_lo = {0.f, 0.f, 0.f, 0.f};
    f32x4 c_hi = {0.f, 0.f, 0.f, 0.f};

    for (int es = e0; es < e1; es += 32) {
        const int last = e1 - 1;
        const int ebase = es + quad * 8;

        int nb[8];
        #pragma unroll
        for (int j = 0; j < 8; ++j) {
            const int e = ebase + j;
            nb[j] = nbr_idx[e < e1 ? e : last];
        }

        bf16x8 afrag, blo, bhi;
        #pragma unroll
        for (int j = 0; j < 8; ++j) {
            const float* pp = points + nb[j] * 3;
            const float rx = pp[0] - ox;
            const float ry = pp[1] - oy;
            const float rz = pp[2] - oz;
            const float dx = rx - kpx, dy = ry - kpy, dz = rz - kpz;
            const float d2 = dx * dx + dy * dy + dz * dz;
            float w = 1.f - sqrtf(d2) * inv_ext;
            w = w > 0.f ? w : 0.f;
            if (l16 >= KP || ebase + j >= e1) w = 0.f;
            afrag[j] = f2bf(w);
        }

        #pragma unroll
        for (int j = 0; j < 8; ++j) {
            const float* fp = features + nb[j] * FIN + l16;
            blo[j] = f2bf(fp[0]);
            bhi[j] = f2bf(fp[16]);
        }

        c_lo = __builtin_amdgcn_mfma_f32_16x16x32_bf16(afrag, blo, c_lo, 0, 0, 0);
        c_hi = __builtin_amdgcn_mfma_f32_16x16x32_bf16(afrag, bhi, c_hi, 0, 0, 0);
    }

    _Float16* dst = agg_g + (size_t)m * KFDIM;
    #pragma unroll
    for (int r = 0; r < 4; ++r) {
        const int krow = quad * 4 + r;
        if (krow < KP) {
            dst[krow * FIN + l16]      = (_Float16)c_lo[r];
            dst[krow * FIN + 16 + l16] = (_Float16)c_hi[r];
        }
    }
}

__global__ __launch_bounds__(256, 4) void kpconv_gemm_plain(
    const _Float16* __restrict__ agg_g,
    const float* __restrict__ k_values,
    float* __restrict__ out)
{
    const int tid  = threadIdx.x;
    const int wave = tid >> 6;
    const int lane = tid & 63;
    const int quad = lane >> 4;
    const int l16  = lane & 15;
    const int m0   = blockIdx.x * 32;
    const int bcol = wave * 16 + l16;

    f16x8 bfr[15];
    #pragma unroll
    for (int s = 0; s < 15; ++s) {
        #pragma unroll
        for (int j = 0; j < 8; ++j)
            bfr[s][j] = (_Float16)k_values[(32 * s + quad * 8 + j) * COUT + bcol];
    }

    const _Float16* arow0 = agg_g + (size_t)(m0 + l16) * KFDIM + quad * 8;
    const _Float16* arow1 = arow0 + 16 * KFDIM;

    f32x4 c0 = {0.f, 0.f, 0.f, 0.f};
    f32x4 c1 = {0.f, 0.f, 0.f, 0.f};
    #pragma unroll
    for (int s = 0; s < 15; ++s) {
        const f16x8 a0 = *(const f16x8*)(arow0 + 32 * s);
        const f16x8 a1 = *(const f16x8*)(arow1 + 32 * s);
        c0 = __builtin_amdgcn_mfma_f32_16x16x32_f16(a0, bfr[s], c0, 0, 0, 0);
        c1 = __builtin_amdgcn_mfma_f32_16x16x32_f16(a1, bfr[s], c1, 0, 0, 0);
    }

    #pragma unroll
    for (int r = 0; r < 4; ++r) {
        out[(m0 + quad * 4 + r) * COUT + bcol]      = c0[r];
        out[(m0 + 16 + quad * 4 + r) * COUT + bcol] = c1[r];
    }
}

extern "C" void kernel_launch(void* const* d_in, const int* in_sizes, int n_in,
                              void* d_out, int out_size, void* d_ws, size_t ws_size,
                              hipStream_t stream) {
    const float* points        = (const float*)d_in[0];
    const float* features      = (const float*)d_in[1];
    const float* output_points = (const float*)d_in[2];
    const int*   nbr_idx       = (const int*)d_in[3];
    const int*   seg_ids       = (const int*)d_in[4];
    const float* k_points      = (const float*)d_in[5];
    const float* k_values      = (const float*)d_in[6];
    float* out = (float*)d_out;

    const size_t feat_bytes = (size_t)NPTS * FIN * sizeof(_Float16);           // 2.56 MB
    const size_t pts4_bytes = (size_t)NPTS * sizeof(float4);                   // 0.64 MB
    const size_t op4_bytes  = (size_t)MOUT * sizeof(float4);                   // 0.64 MB
    const size_t rs_bytes   = ((size_t)(MOUT + 1) * sizeof(int) + 15) & ~15ul; // 160 KB
    const size_t wt_bytes   = (size_t)KFDIM * COUT * sizeof(_Float16);         // 60 KB
    const size_t full_bytes = feat_bytes + pts4_bytes + op4_bytes + rs_bytes
                            + wt_bytes;                                        // ~4.1 MB

    if (ws_size >= full_bytes) {
        char* p = (char*)d_ws;
        _Float16* feat_i    = (_Float16*)p;  p += feat_bytes;
        float4*   points4   = (float4*)p;    p += pts4_bytes;
        float4*   op4       = (float4*)p;    p += op4_bytes;
        int*      row_start = (int*)p;       p += rs_bytes;
        _Float16* w_t       = (_Float16*)p;

        preprocess_all<<<PRE_BLKS, 256, 0, stream>>>(
            features, feat_i, points, points4, output_points, op4,
            seg_ids, row_start, k_values, w_t);
        kpconv_fused2<<<MOUT / 16, 256, 0, stream>>>(
            points4, feat_i, op4, nbr_idx, row_start, k_points, w_t, out);
    } else {
        _Float16* agg_g = (_Float16*)d_ws;   // needs 38.4 MB
        kpconv_agg_fallback<<<MOUT / 4, 256, 0, stream>>>(
            points, features, output_points, nbr_idx, seg_ids, k_points, agg_g);
        kpconv_gemm_plain<<<MOUT / 32, 256, 0, stream>>>(agg_g, k_values, out);
    }
}